// Round 5
// baseline (1216.371 us; speedup 1.0000x reference)
//
#include <hip/hip_runtime.h>
#include <cstdint>
#include <cstddef>

// ---------------------------------------------------------------------------
// LASAGE R5:
//   - XCD-sliced aggregation: 8 column-slices of 32 bf16 cols (64 B/row);
//     slice table = 3.2 MB < 4 MB per-XCD L2; slice = blockIdx & 7 rides the
//     round-robin block->XCD dispatch so re-reads stay in-XCD-L2.
//     2 edges per wave (half-wave each), __shfl_xor(32) combine.
//   - MFMA GEMM widened to 128x128 tiles (NT=8 n-tiles), NT=4 for final.
//   - 8 weight-conversion launches merged into 1.
//   - Buffers: xc bf16[N,256] over d_in[0]; h bf16 -> d_in[1]; hm bf16 ->
//     d_in[0]; agg bf16 in ws; d_out written only by final fp32 GEMM.
// ---------------------------------------------------------------------------

typedef __attribute__((ext_vector_type(8))) short short8;   // 8 x bf16
typedef __attribute__((ext_vector_type(4))) float f32x4;    // MFMA acc

#define F_RELU  1
#define F_F32OUT 2

__device__ __forceinline__ ushort f2bf(float f) {
    unsigned u = __float_as_uint(f);
    u += 0x7fffu + ((u >> 16) & 1u);   // round-to-nearest-even
    return (ushort)(u >> 16);
}
__device__ __forceinline__ float bf2f(ushort u) {
    return __uint_as_float((unsigned)u << 16);
}

// ---------------- CSR construction (verified R3/R4) ----------------

__global__ void deg_kernel(const int* __restrict__ dst, int* __restrict__ deg, int E) {
    int i = blockIdx.x * blockDim.x + threadIdx.x;
    if (i < E) atomicAdd(&deg[dst[i]], 1);
}

__global__ void chunk_sum_kernel(const int* __restrict__ deg,
                                 int* __restrict__ csum, int N, int CH) {
    int t = blockIdx.x * blockDim.x + threadIdx.x;
    int beg = t * CH, end = min(beg + CH, N);
    int s = 0;
    for (int i = beg; i < end; ++i) s += deg[i];
    csum[t] = s;
}

__global__ void scan1024_kernel(const int* __restrict__ csum, int* __restrict__ coff) {
    __shared__ int sh[1024];
    int t = threadIdx.x;
    int v0 = csum[t];
    sh[t] = v0;
    __syncthreads();
    for (int off = 1; off < 1024; off <<= 1) {
        int v = (t >= off) ? sh[t - off] : 0;
        __syncthreads();
        sh[t] += v;
        __syncthreads();
    }
    coff[t] = sh[t] - v0;
}

__global__ void rowptr_kernel(const int* __restrict__ deg, const int* __restrict__ coff,
                              int* __restrict__ rowptr, int N, int CH, int E) {
    int t = blockIdx.x * blockDim.x + threadIdx.x;
    int beg = t * CH, end = min(beg + CH, N);
    int run = coff[t];
    for (int i = beg; i < end; ++i) { rowptr[i] = run; run += deg[i]; }
    if (t == 0) rowptr[N] = E;
}

__global__ void scatter_kernel(const int* __restrict__ src, const int* __restrict__ dst,
                               const int* __restrict__ rowptr, int* __restrict__ cursor,
                               int* __restrict__ col, int E) {
    int i = blockIdx.x * blockDim.x + threadIdx.x;
    if (i < E) {
        int d = dst[i];
        int pos = atomicAdd(&cursor[d], 1);
        col[rowptr[d] + pos] = src[i];
    }
}

// ---------------- conversions ----------------

// xc[n][0:128]=bf16(x0[n]), xc[n][128:256]=bf16(x1[n]); xc ALIASES x0's buffer.
// No __restrict__: may-alias keeps loads ordered before stores (wave lockstep).
__global__ void conv_x_kernel(const float* x0, const float* x1, ushort* xc, int N) {
    int gid = blockIdx.x * blockDim.x + threadIdx.x;
    int w = gid >> 6, lane = gid & 63;
    if (w >= N) return;
    float2 a = *((const float2*)(x0 + (size_t)w * 128) + lane);
    float2 b = *((const float2*)(x1 + (size_t)w * 128) + lane);
    ushort2 ua; ua.x = f2bf(a.x); ua.y = f2bf(a.y);
    ushort2 ub; ub.x = f2bf(b.x); ub.y = f2bf(b.y);
    *((ushort2*)(xc + (size_t)w * 256) + lane) = ua;
    *((ushort2*)(xc + (size_t)w * 256 + 128) + lane) = ub;
}

// All 8 weight matrices -> bf16, transposed to [n][K], in one dispatch.
__global__ void conv_w_all_kernel(
    const float* __restrict__ Wl0, const float* __restrict__ Wr0,
    const float* __restrict__ Wl1, const float* __restrict__ Wr1,
    const float* __restrict__ Wlm, const float* __restrict__ Wrm,
    const float* __restrict__ Wlo, const float* __restrict__ Wro,
    ushort* __restrict__ Wl0t, ushort* __restrict__ Wr0t,
    ushort* __restrict__ Wl1t, ushort* __restrict__ Wr1t,
    ushort* __restrict__ Wlmt, ushort* __restrict__ Wrmt,
    ushort* __restrict__ Wlot, ushort* __restrict__ Wrot) {
    int idx = blockIdx.x * blockDim.x + threadIdx.x;
    const float* W; ushort* Wt; int K, Ncol;
    if      (idx < 16384)  { W = Wl0; Wt = Wl0t; K = 128; Ncol = 128; }
    else if (idx < 32768)  { W = Wr0; Wt = Wr0t; K = 128; Ncol = 128; idx -= 16384; }
    else if (idx < 49152)  { W = Wl1; Wt = Wl1t; K = 128; Ncol = 128; idx -= 32768; }
    else if (idx < 65536)  { W = Wr1; Wt = Wr1t; K = 128; Ncol = 128; idx -= 49152; }
    else if (idx < 131072) { W = Wlm; Wt = Wlmt; K = 256; Ncol = 256; idx -= 65536; }
    else if (idx < 196608) { W = Wrm; Wt = Wrmt; K = 256; Ncol = 256; idx -= 131072; }
    else if (idx < 212992) { W = Wlo; Wt = Wlot; K = 256; Ncol = 64;  idx -= 196608; }
    else if (idx < 229376) { W = Wro; Wt = Wrot; K = 256; Ncol = 64;  idx -= 212992; }
    else return;
    int k = idx / Ncol, n = idx - k * Ncol;
    Wt[(size_t)n * K + k] = f2bf(W[(size_t)k * Ncol + n]);
}

// ---------------- XCD-sliced aggregation ----------------
// Grid: 8 * ceil(N/4) blocks of 256. slice = blockIdx & 7 (rides round-robin
// block->XCD dispatch: slice table N*64B = 3.2MB fits 4MB per-XCD L2).
// Wave = one node; half-wave per edge (2 edges in flight); lane&31 = column.
__global__ void agg_slice_kernel(const ushort* __restrict__ src,
                                 const int* __restrict__ rowptr,
                                 const int* __restrict__ col,
                                 ushort* __restrict__ outt, int N) {
    int b = blockIdx.x;
    int slice = b & 7;
    int grp = b >> 3;
    int wave = threadIdx.x >> 6, lane = threadIdx.x & 63;
    int w = grp * 4 + wave;
    if (w >= N) return;
    int half = lane >> 5;   // which edge of the pair
    int c32 = lane & 31;    // column within slice
    int beg = rowptr[w], end = rowptr[w + 1];
    const ushort* base = src + slice * 32 + c32;
    float s = 0.f;
    for (int k = beg + half; k < end; k += 2)
        s += bf2f(base[(size_t)col[k] * 256]);
    s += __shfl_xor(s, 32);   // combine the two half-wave partial sums
    if (lane < 32) {
        float inv = 1.0f / (float)max(end - beg, 1);
        outt[(size_t)w * 256 + slice * 32 + c32] = f2bf(s * inv);
    }
}

// ---------------- bf16 MFMA GEMM, dual-A fused, templated n-width ----------
// C = A1 @ W1 + A2 @ W2 + bias (+relu). A: [M,K] bf16 row-major (stride lda).
// Wt: [ncols][K] bf16 k-major. 256 thr = 4 waves; tile 128m x (NT*16)n;
// wave w: rows w*32..w*32+31 (2 m-tiles) x NT n-tiles.
// LDS rows padded to 40 bf16 (80B): b128 reads ~2-way on banks (free, m136).
template <int NT>
__global__ __launch_bounds__(256) void mfma_gemm_kernel(
    const ushort* __restrict__ A1, const ushort* __restrict__ A2, int lda, int K,
    const ushort* __restrict__ Wt1, const ushort* __restrict__ Wt2,
    const float* __restrict__ bias, void* __restrict__ Cout, int ldc,
    int M, int flags) {
    __shared__ __align__(16) ushort As[128 * 40];
    __shared__ __align__(16) ushort Bs[NT * 16 * 40];

    int tid = threadIdx.x;
    int m0 = blockIdx.x * 128, n0 = blockIdx.y * (NT * 16);
    int wave = tid >> 6, lane = tid & 63;
    int lr = lane & 15, lq = lane >> 4;

    f32x4 acc[2][NT];
#pragma unroll
    for (int i = 0; i < 2; ++i)
#pragma unroll
        for (int j = 0; j < NT; ++j) acc[i][j] = (f32x4){0.f, 0.f, 0.f, 0.f};

    int q = tid & 3;     // 16B (8 bf16) chunk within a 32-k row segment
    int r0 = tid >> 2;   // 0..63

    for (int p = 0; p < 2; ++p) {
        const ushort* A = p ? A2 : A1;
        const ushort* W = p ? Wt2 : Wt1;
        for (int k0 = 0; k0 < K; k0 += 32) {
            // stage A tile: 128 rows x 32 k
#pragma unroll
            for (int it = 0; it < 2; ++it) {
                int r = r0 + 64 * it;
                int m = m0 + r;
                float4 t = make_float4(0.f, 0.f, 0.f, 0.f);
                if (m < M) t = *(const float4*)(A + (size_t)m * lda + k0 + q * 8);
                *(float4*)&As[r * 40 + q * 8] = t;
            }
            // stage B tile: NT*16 n-rows x 32 k
#pragma unroll
            for (int it = 0; it < NT / 4; ++it) {
                int r = r0 + 64 * it;
                float4 t = *(const float4*)(W + (size_t)(n0 + r) * K + k0 + q * 8);
                *(float4*)&Bs[r * 40 + q * 8] = t;
            }
            __syncthreads();
            short8 a[2], b[NT];
#pragma unroll
            for (int mt = 0; mt < 2; ++mt)
                a[mt] = *(const short8*)&As[(wave * 32 + mt * 16 + lr) * 40 + lq * 8];
#pragma unroll
            for (int nt = 0; nt < NT; ++nt)
                b[nt] = *(const short8*)&Bs[(nt * 16 + lr) * 40 + lq * 8];
#pragma unroll
            for (int mt = 0; mt < 2; ++mt)
#pragma unroll
                for (int nt = 0; nt < NT; ++nt)
                    acc[mt][nt] = __builtin_amdgcn_mfma_f32_16x16x32_bf16(
                        a[mt], b[nt], acc[mt][nt], 0, 0, 0);
            __syncthreads();
        }
    }

    // epilogue: C/D layout col = lane&15, row = (lane>>4)*4 + reg  [m89]
#pragma unroll
    for (int nt = 0; nt < NT; ++nt) {
        int n = n0 + nt * 16 + lr;
        float bv = bias[n];
#pragma unroll
        for (int mt = 0; mt < 2; ++mt) {
#pragma unroll
            for (int r = 0; r < 4; ++r) {
                int m = m0 + wave * 32 + mt * 16 + lq * 4 + r;
                if (m >= M) continue;
                float v = acc[mt][nt][r] + bv;
                if (flags & F_RELU) v = fmaxf(v, 0.f);
                if (flags & F_F32OUT)
                    ((float*)Cout)[(size_t)m * ldc + n] = v;
                else
                    ((ushort*)Cout)[(size_t)m * ldc + n] = f2bf(v);
            }
        }
    }
}

// ---------------------------------------------------------------------------

extern "C" void kernel_launch(void* const* d_in, const int* in_sizes, int n_in,
                              void* d_out, int out_size, void* d_ws, size_t ws_size,
                              hipStream_t stream) {
    const float* x0 = (const float*)d_in[0];
    const float* x1 = (const float*)d_in[1];
    const int* ei = (const int*)d_in[2];  // integer inputs arrive as int32
    const float* Wl0 = (const float*)d_in[3];
    const float* Wr0 = (const float*)d_in[4];
    const float* b0 = (const float*)d_in[5];
    const float* Wl1 = (const float*)d_in[6];
    const float* Wr1 = (const float*)d_in[7];
    const float* b1 = (const float*)d_in[8];
    const float* Wlm = (const float*)d_in[9];
    const float* Wrm = (const float*)d_in[10];
    const float* bm = (const float*)d_in[11];
    const float* Wlo = (const float*)d_in[12];
    const float* Wro = (const float*)d_in[13];
    const float* bo = (const float*)d_in[14];

    const int N = in_sizes[0] / 128;
    const int E = in_sizes[2] / 2;
    const int* srcI = ei;
    const int* dstI = ei + E;

    // activation buffers aliased onto the (restored-each-call) input buffers
    ushort* xc  = (ushort*)d_in[0];  // [N,256] bf16 over x0's fp32 buf
    ushort* hb  = (ushort*)d_in[1];  // [N,256] bf16 over x1's buf
    ushort* hmb = (ushort*)d_in[0];  // [N,256] bf16 over xc (dead post-L0/L1)
    float* out = (float*)d_out;

    // ---- ws carve ----
    char* ws = (char*)d_ws;
    size_t used = 0;
    auto carve = [&](size_t bytes) {
        char* p = ws + used;
        used += (bytes + 63) & ~(size_t)63;
        return p;
    };
    int* deg = (int*)carve((size_t)2 * N * 4);
    int* cursor = deg + N;
    int* csum = (int*)carve(1024 * 4);
    int* coff = (int*)carve(1024 * 4);
    int* rowptr = (int*)carve((size_t)(N + 1) * 4);
    int* col = (int*)carve((size_t)E * 4);
    ushort* aggb = (ushort*)carve((size_t)N * 256 * 2);
    ushort* Wl0t = (ushort*)carve(128 * 128 * 2);
    ushort* Wr0t = (ushort*)carve(128 * 128 * 2);
    ushort* Wl1t = (ushort*)carve(128 * 128 * 2);
    ushort* Wr1t = (ushort*)carve(128 * 128 * 2);
    ushort* Wlmt = (ushort*)carve(256 * 256 * 2);
    ushort* Wrmt = (ushort*)carve(256 * 256 * 2);
    ushort* Wlot = (ushort*)carve(256 * 64 * 2);
    ushort* Wrot = (ushort*)carve(256 * 64 * 2);
    if (used > ws_size) return;  // fail clean, not with a mem fault

    const int CH = (N + 1023) / 1024;
    const int eb = (E + 255) / 256;
    const int ab = (N * 64 + 255) / 256;        // wave-per-node grid
    const int sb = 8 * ((N + 3) / 4);           // sliced agg grid
    const int mb = (N + 127) / 128;             // GEMM 128-row tiles

    // ---- CSR ----
    hipMemsetAsync(deg, 0, (size_t)2 * N * 4, stream);
    deg_kernel<<<eb, 256, 0, stream>>>(dstI, deg, E);
    chunk_sum_kernel<<<4, 256, 0, stream>>>(deg, csum, N, CH);
    scan1024_kernel<<<1, 1024, 0, stream>>>(csum, coff);
    rowptr_kernel<<<4, 256, 0, stream>>>(deg, coff, rowptr, N, CH, E);
    scatter_kernel<<<eb, 256, 0, stream>>>(srcI, dstI, rowptr, cursor, col, E);

    // ---- conversions ----
    conv_x_kernel<<<ab, 256, 0, stream>>>(x0, x1, xc, N);
    conv_w_all_kernel<<<(229376 + 255) / 256, 256, 0, stream>>>(
        Wl0, Wr0, Wl1, Wr1, Wlm, Wrm, Wlo, Wro,
        Wl0t, Wr0t, Wl1t, Wr1t, Wlmt, Wrmt, Wlot, Wrot);

    // ---- layer 0/1 ----
    agg_slice_kernel<<<sb, 256, 0, stream>>>(xc, rowptr, col, aggb, N);
    mfma_gemm_kernel<8><<<dim3(mb, 1), 256, 0, stream>>>(
        aggb, xc, 256, 128, Wl0t, Wr0t, b0, hb, 256, N, F_RELU);
    mfma_gemm_kernel<8><<<dim3(mb, 1), 256, 0, stream>>>(
        aggb + 128, xc + 128, 256, 128, Wl1t, Wr1t, b1, hb + 128, 256, N, F_RELU);

    // ---- middle conv ----
    agg_slice_kernel<<<sb, 256, 0, stream>>>(hb, rowptr, col, aggb, N);
    mfma_gemm_kernel<8><<<dim3(mb, 2), 256, 0, stream>>>(
        aggb, hb, 256, 256, Wlmt, Wrmt, bm, hmb, 256, N, F_RELU);

    // ---- final conv (fp32 out) ----
    agg_slice_kernel<<<sb, 256, 0, stream>>>(hmb, rowptr, col, aggb, N);
    mfma_gemm_kernel<4><<<dim3(mb, 1), 256, 0, stream>>>(
        aggb, hmb, 256, 256, Wlot, Wrot, bo, out, 64, N, F_F32OUT);
}

// Round 6
// 594.561 us; speedup vs baseline: 2.0458x; 2.0458x over previous
//
#include <hip/hip_runtime.h>
#include <cstdint>
#include <cstddef>

// ---------------------------------------------------------------------------
// LASAGE R6:
//   - Aggregation reverted to R4's wave-per-node 256-col bf16 gather
//     (512 B/edge per instruction; R5's 64 B slicing was latency-bound).
//   - Final layer commuted: Z = hm@Wlo (bf16 [N,64], 6.4 MB table), then
//     out = hm@Wro + bo, then out += mean-agg(Z)  (agg(hm)@Wlo == agg(hm@Wlo)).
//   - Weights-stationary MFMA GEMM: weight block staged to LDS ONCE (single
//     barrier), K-loop loads A fragments directly global->VGPR, MFMA
//     back-to-back, zero barriers in the loop. K templated (128/256), fully
//     unrolled. LDS rows padded to K+8 -> uniform bank spread for b128.
//   - Buffers: xc bf16[N,256] over d_in[0]; h bf16 -> d_in[1]; hm bf16 ->
//     d_in[0]; agg + Z + weights in ws; d_out written by final GEMM then
//     accumulated by agg64_add.
// ---------------------------------------------------------------------------

typedef __attribute__((ext_vector_type(8))) short short8;   // 8 x bf16
typedef __attribute__((ext_vector_type(4))) float f32x4;    // MFMA acc

#define F_RELU   1
#define F_F32OUT 2

__device__ __forceinline__ ushort f2bf(float f) {
    unsigned u = __float_as_uint(f);
    u += 0x7fffu + ((u >> 16) & 1u);   // round-to-nearest-even
    return (ushort)(u >> 16);
}
__device__ __forceinline__ float bf2f(ushort u) {
    return __uint_as_float((unsigned)u << 16);
}

// ---------------- CSR construction (verified R3/R4) ----------------

__global__ void deg_kernel(const int* __restrict__ dst, int* __restrict__ deg, int E) {
    int i = blockIdx.x * blockDim.x + threadIdx.x;
    if (i < E) atomicAdd(&deg[dst[i]], 1);
}

__global__ void chunk_sum_kernel(const int* __restrict__ deg,
                                 int* __restrict__ csum, int N, int CH) {
    int t = blockIdx.x * blockDim.x + threadIdx.x;
    int beg = t * CH, end = min(beg + CH, N);
    int s = 0;
    for (int i = beg; i < end; ++i) s += deg[i];
    csum[t] = s;
}

__global__ void scan1024_kernel(const int* __restrict__ csum, int* __restrict__ coff) {
    __shared__ int sh[1024];
    int t = threadIdx.x;
    int v0 = csum[t];
    sh[t] = v0;
    __syncthreads();
    for (int off = 1; off < 1024; off <<= 1) {
        int v = (t >= off) ? sh[t - off] : 0;
        __syncthreads();
        sh[t] += v;
        __syncthreads();
    }
    coff[t] = sh[t] - v0;
}

__global__ void rowptr_kernel(const int* __restrict__ deg, const int* __restrict__ coff,
                              int* __restrict__ rowptr, int N, int CH, int E) {
    int t = blockIdx.x * blockDim.x + threadIdx.x;
    int beg = t * CH, end = min(beg + CH, N);
    int run = coff[t];
    for (int i = beg; i < end; ++i) { rowptr[i] = run; run += deg[i]; }
    if (t == 0) rowptr[N] = E;
}

__global__ void scatter_kernel(const int* __restrict__ src, const int* __restrict__ dst,
                               const int* __restrict__ rowptr, int* __restrict__ cursor,
                               int* __restrict__ col, int E) {
    int i = blockIdx.x * blockDim.x + threadIdx.x;
    if (i < E) {
        int d = dst[i];
        int pos = atomicAdd(&cursor[d], 1);
        col[rowptr[d] + pos] = src[i];
    }
}

// ---------------- conversions ----------------

// xc[n][0:128]=bf16(x0[n]), xc[n][128:256]=bf16(x1[n]); xc ALIASES x0's buffer.
// No __restrict__: may-alias keeps loads ordered before stores (wave lockstep).
__global__ void conv_x_kernel(const float* x0, const float* x1, ushort* xc, int N) {
    int gid = blockIdx.x * blockDim.x + threadIdx.x;
    int w = gid >> 6, lane = gid & 63;
    if (w >= N) return;
    float2 a = *((const float2*)(x0 + (size_t)w * 128) + lane);
    float2 b = *((const float2*)(x1 + (size_t)w * 128) + lane);
    ushort2 ua; ua.x = f2bf(a.x); ua.y = f2bf(a.y);
    ushort2 ub; ub.x = f2bf(b.x); ub.y = f2bf(b.y);
    *((ushort2*)(xc + (size_t)w * 256) + lane) = ua;
    *((ushort2*)(xc + (size_t)w * 256 + 128) + lane) = ub;
}

// All 8 weight matrices -> bf16, transposed to [n][K], in one dispatch.
__global__ void conv_w_all_kernel(
    const float* __restrict__ Wl0, const float* __restrict__ Wr0,
    const float* __restrict__ Wl1, const float* __restrict__ Wr1,
    const float* __restrict__ Wlm, const float* __restrict__ Wrm,
    const float* __restrict__ Wlo, const float* __restrict__ Wro,
    ushort* __restrict__ Wl0t, ushort* __restrict__ Wr0t,
    ushort* __restrict__ Wl1t, ushort* __restrict__ Wr1t,
    ushort* __restrict__ Wlmt, ushort* __restrict__ Wrmt,
    ushort* __restrict__ Wlot, ushort* __restrict__ Wrot) {
    int idx = blockIdx.x * blockDim.x + threadIdx.x;
    const float* W; ushort* Wt; int K, Ncol;
    if      (idx < 16384)  { W = Wl0; Wt = Wl0t; K = 128; Ncol = 128; }
    else if (idx < 32768)  { W = Wr0; Wt = Wr0t; K = 128; Ncol = 128; idx -= 16384; }
    else if (idx < 49152)  { W = Wl1; Wt = Wl1t; K = 128; Ncol = 128; idx -= 32768; }
    else if (idx < 65536)  { W = Wr1; Wt = Wr1t; K = 128; Ncol = 128; idx -= 49152; }
    else if (idx < 131072) { W = Wlm; Wt = Wlmt; K = 256; Ncol = 256; idx -= 65536; }
    else if (idx < 196608) { W = Wrm; Wt = Wrmt; K = 256; Ncol = 256; idx -= 131072; }
    else if (idx < 212992) { W = Wlo; Wt = Wlot; K = 256; Ncol = 64;  idx -= 196608; }
    else if (idx < 229376) { W = Wro; Wt = Wrot; K = 256; Ncol = 64;  idx -= 212992; }
    else return;
    int k = idx / Ncol, n = idx - k * Ncol;
    Wt[(size_t)n * K + k] = f2bf(W[(size_t)k * Ncol + n]);
}

// ---------------- aggregation: wave per node, 256 bf16 cols (R4) ----------

__global__ void agg_bf16_kernel(const ushort* __restrict__ src,
                                const int* __restrict__ rowptr,
                                const int* __restrict__ col,
                                ushort* __restrict__ outt, int N) {
    int gid = blockIdx.x * blockDim.x + threadIdx.x;
    int w = gid >> 6, lane = gid & 63;
    if (w >= N) return;
    int beg = rowptr[w], end = rowptr[w + 1];
    float s0 = 0.f, s1 = 0.f, s2 = 0.f, s3 = 0.f;
    for (int k = beg; k < end; ++k) {
        int c = col[k];
        ushort4 v = *((const ushort4*)(src + (size_t)c * 256) + lane);
        s0 += bf2f(v.x); s1 += bf2f(v.y); s2 += bf2f(v.z); s3 += bf2f(v.w);
    }
    float inv = 1.0f / (float)max(end - beg, 1);
    ushort4 o;
    o.x = f2bf(s0 * inv); o.y = f2bf(s1 * inv);
    o.z = f2bf(s2 * inv); o.w = f2bf(s3 * inv);
    *((ushort4*)(outt + (size_t)w * 256) + lane) = o;
}

// ---------------- agg of 64-col bf16 table, accumulate into fp32 out ------
// out[w][lane] += mean_{nbr} Z[nbr][lane].  128 B/edge per instruction.
__global__ void agg64_add_kernel(const ushort* __restrict__ Z,
                                 const int* __restrict__ rowptr,
                                 const int* __restrict__ col,
                                 float* __restrict__ out, int N) {
    int gid = blockIdx.x * blockDim.x + threadIdx.x;
    int w = gid >> 6, lane = gid & 63;
    if (w >= N) return;
    int beg = rowptr[w], end = rowptr[w + 1];
    float s = 0.f;
    for (int k = beg; k < end; ++k)
        s += bf2f(Z[(size_t)col[k] * 64 + lane]);
    float inv = 1.0f / (float)max(end - beg, 1);
    out[(size_t)w * 64 + lane] += s * inv;
}

// ---------------- weights-stationary MFMA GEMM ----------------
// C = A1 @ W1 (+ A2 @ W2) + bias (+relu).  A: [M,K] bf16 row-major, stride
// lda (shared).  Wt: [ncols][K] bf16 k-major.  Block = 256 thr = 4 waves;
// tile 128m x 64n; wave w: rows w*32..w*32+31 (2 m-tiles) x 4 n-tiles.
// Weight block (64 rows x K, both passes) staged to LDS ONCE -> single
// barrier; K-loop: A frags loaded global->VGPR directly (16 rows x 64 B per
// instruction), B frags from LDS, MFMA back-to-back, no barriers.
// LDS row stride K+8 elems: bank = 4*(lr+lq) mod 32 -> uniform 8 groups.
template <int K>
__global__ __launch_bounds__(256) void ws_gemm_kernel(
    const ushort* __restrict__ A1, const ushort* __restrict__ A2, int lda,
    const ushort* __restrict__ Wt1, const ushort* __restrict__ Wt2,
    const float* __restrict__ bias, void* __restrict__ Cout, int ldc,
    int M, int flags) {
    constexpr int PK = K + 8;
    __shared__ __align__(16) ushort Bs[2][64 * PK];

    int tid = threadIdx.x;
    int m0 = blockIdx.x * 128, n0 = blockIdx.y * 64;
    int wave = tid >> 6, lane = tid & 63;
    int lr = lane & 15, lq = lane >> 4;
    int npass = A2 ? 2 : 1;

    // ---- stage weight block(s): rows n0..n0+63, K cols ----
    {
        int r = tid >> 2;              // 0..63
        int c0 = (tid & 3) * 8;        // 16B chunks, stride 32 elems
        for (int p = 0; p < npass; ++p) {
            const ushort* W = (p ? Wt2 : Wt1) + (size_t)(n0 + r) * K;
#pragma unroll
            for (int c = 0; c < K; c += 32)
                *(float4*)&Bs[p][r * PK + c + c0] = *(const float4*)(W + c + c0);
        }
    }
    __syncthreads();

    f32x4 acc[2][4];
#pragma unroll
    for (int i = 0; i < 2; ++i)
#pragma unroll
        for (int j = 0; j < 4; ++j) acc[i][j] = (f32x4){0.f, 0.f, 0.f, 0.f};

    for (int p = 0; p < npass; ++p) {
        const ushort* A = p ? A2 : A1;
#pragma unroll
        for (int k0 = 0; k0 < K; k0 += 32) {
            short8 a[2], b[4];
#pragma unroll
            for (int mt = 0; mt < 2; ++mt) {
                int m = m0 + wave * 32 + mt * 16 + lr;
                m = min(m, M - 1);  // clamp: garbage rows never stored
                a[mt] = *(const short8*)(A + (size_t)m * lda + k0 + lq * 8);
            }
#pragma unroll
            for (int nt = 0; nt < 4; ++nt)
                b[nt] = *(const short8*)&Bs[p][(nt * 16 + lr) * PK + k0 + lq * 8];
#pragma unroll
            for (int mt = 0; mt < 2; ++mt)
#pragma unroll
                for (int nt = 0; nt < 4; ++nt)
                    acc[mt][nt] = __builtin_amdgcn_mfma_f32_16x16x32_bf16(
                        a[mt], b[nt], acc[mt][nt], 0, 0, 0);
        }
    }

    // epilogue: C/D layout col = lane&15, row = (lane>>4)*4 + reg  [m89]
#pragma unroll
    for (int nt = 0; nt < 4; ++nt) {
        int n = n0 + nt * 16 + lr;
        float bv = bias ? bias[n] : 0.f;
#pragma unroll
        for (int mt = 0; mt < 2; ++mt) {
#pragma unroll
            for (int r = 0; r < 4; ++r) {
                int m = m0 + wave * 32 + mt * 16 + lq * 4 + r;
                if (m >= M) continue;
                float v = acc[mt][nt][r] + bv;
                if (flags & F_RELU) v = fmaxf(v, 0.f);
                if (flags & F_F32OUT)
                    ((float*)Cout)[(size_t)m * ldc + n] = v;
                else
                    ((ushort*)Cout)[(size_t)m * ldc + n] = f2bf(v);
            }
        }
    }
}

// ---------------------------------------------------------------------------

extern "C" void kernel_launch(void* const* d_in, const int* in_sizes, int n_in,
                              void* d_out, int out_size, void* d_ws, size_t ws_size,
                              hipStream_t stream) {
    const float* x0 = (const float*)d_in[0];
    const float* x1 = (const float*)d_in[1];
    const int* ei = (const int*)d_in[2];  // integer inputs arrive as int32
    const float* Wl0 = (const float*)d_in[3];
    const float* Wr0 = (const float*)d_in[4];
    const float* b0 = (const float*)d_in[5];
    const float* Wl1 = (const float*)d_in[6];
    const float* Wr1 = (const float*)d_in[7];
    const float* b1 = (const float*)d_in[8];
    const float* Wlm = (const float*)d_in[9];
    const float* Wrm = (const float*)d_in[10];
    const float* bm = (const float*)d_in[11];
    const float* Wlo = (const float*)d_in[12];
    const float* Wro = (const float*)d_in[13];
    const float* bo = (const float*)d_in[14];

    const int N = in_sizes[0] / 128;
    const int E = in_sizes[2] / 2;
    const int* srcI = ei;
    const int* dstI = ei + E;

    // activation buffers aliased onto the (restored-each-call) input buffers
    ushort* xc  = (ushort*)d_in[0];  // [N,256] bf16 over x0's fp32 buf
    ushort* hb  = (ushort*)d_in[1];  // [N,256] bf16 over x1's buf
    ushort* hmb = (ushort*)d_in[0];  // [N,256] bf16 over xc (dead post-L0/L1)
    float* out = (float*)d_out;

    // ---- ws carve ----
    char* ws = (char*)d_ws;
    size_t used = 0;
    auto carve = [&](size_t bytes) {
        char* p = ws + used;
        used += (bytes + 63) & ~(size_t)63;
        return p;
    };
    int* deg = (int*)carve((size_t)2 * N * 4);
    int* cursor = deg + N;
    int* csum = (int*)carve(1024 * 4);
    int* coff = (int*)carve(1024 * 4);
    int* rowptr = (int*)carve((size_t)(N + 1) * 4);
    int* col = (int*)carve((size_t)E * 4);
    ushort* aggb = (ushort*)carve((size_t)N * 256 * 2);
    ushort* Zb   = (ushort*)carve((size_t)N * 64 * 2);   // final-layer Z=hm@Wlo
    ushort* Wl0t = (ushort*)carve(128 * 128 * 2);
    ushort* Wr0t = (ushort*)carve(128 * 128 * 2);
    ushort* Wl1t = (ushort*)carve(128 * 128 * 2);
    ushort* Wr1t = (ushort*)carve(128 * 128 * 2);
    ushort* Wlmt = (ushort*)carve(256 * 256 * 2);
    ushort* Wrmt = (ushort*)carve(256 * 256 * 2);
    ushort* Wlot = (ushort*)carve(256 * 64 * 2);
    ushort* Wrot = (ushort*)carve(256 * 64 * 2);
    if (used > ws_size) return;  // fail clean, not with a mem fault

    const int CH = (N + 1023) / 1024;
    const int eb = (E + 255) / 256;
    const int ab = (N * 64 + 255) / 256;   // wave-per-node grid
    const int mb = (N + 127) / 128;        // GEMM 128-row tiles
    const ushort* UN = nullptr;

    // ---- CSR ----
    hipMemsetAsync(deg, 0, (size_t)2 * N * 4, stream);
    deg_kernel<<<eb, 256, 0, stream>>>(dstI, deg, E);
    chunk_sum_kernel<<<4, 256, 0, stream>>>(deg, csum, N, CH);
    scan1024_kernel<<<1, 1024, 0, stream>>>(csum, coff);
    rowptr_kernel<<<4, 256, 0, stream>>>(deg, coff, rowptr, N, CH, E);
    scatter_kernel<<<eb, 256, 0, stream>>>(srcI, dstI, rowptr, cursor, col, E);

    // ---- conversions ----
    conv_x_kernel<<<ab, 256, 0, stream>>>(x0, x1, xc, N);
    conv_w_all_kernel<<<(229376 + 255) / 256, 256, 0, stream>>>(
        Wl0, Wr0, Wl1, Wr1, Wlm, Wrm, Wlo, Wro,
        Wl0t, Wr0t, Wl1t, Wr1t, Wlmt, Wrmt, Wlot, Wrot);

    // ---- layer 0/1: h = relu([agg|self] @ [Wl;Wr] + b), concat halves ----
    agg_bf16_kernel<<<ab, 256, 0, stream>>>(xc, rowptr, col, aggb, N);
    ws_gemm_kernel<128><<<dim3(mb, 2), 256, 0, stream>>>(
        aggb, xc, 256, Wl0t, Wr0t, b0, hb, 256, N, F_RELU);
    ws_gemm_kernel<128><<<dim3(mb, 2), 256, 0, stream>>>(
        aggb + 128, xc + 128, 256, Wl1t, Wr1t, b1, hb + 128, 256, N, F_RELU);

    // ---- middle conv: hm = relu(agg(h) @ Wlm + h @ Wrm + bm) ----
    agg_bf16_kernel<<<ab, 256, 0, stream>>>(hb, rowptr, col, aggb, N);
    ws_gemm_kernel<256><<<dim3(mb, 4), 256, 0, stream>>>(
        aggb, hb, 256, Wlmt, Wrmt, bm, hmb, 256, N, F_RELU);

    // ---- final conv (commuted): out = agg(hm@Wlo) + hm@Wro + bo ----
    ws_gemm_kernel<256><<<dim3(mb, 1), 256, 0, stream>>>(
        hmb, UN, 256, Wlot, UN, nullptr, Zb, 64, N, 0);          // Z bf16
    ws_gemm_kernel<256><<<dim3(mb, 1), 256, 0, stream>>>(
        hmb, UN, 256, Wrot, UN, bo, out, 64, N, F_F32OUT);       // self + bias
    agg64_add_kernel<<<ab, 256, 0, stream>>>(Zb, rowptr, col, out, N);
}